// Round 2
// baseline (463.185 us; speedup 1.0000x reference)
//
#include <hip/hip_runtime.h>
#include <hip/hip_bf16.h>
#include <math.h>

#define N_NODES 100000
#define N_EDGES 1600000
#define F 128
#define OUT_C 64
#define NUM_CLASSES 40
#define BN_EPS 1e-5f

#define NBUCK 782   // ceil(100000/128) buckets of 128 destination nodes
#define BCAP 4096   // per-bucket edge capacity
#define FILL_BLOCKS 512
#define EPB ((N_EDGES + FILL_BLOCKS - 1) / FILL_BLOCKS)  // 3125

typedef __hip_bfloat16 bf16;
typedef __attribute__((ext_vector_type(8))) short bf16x8;
typedef __attribute__((ext_vector_type(4))) float f32x4;

// ---- fp32 param block offsets ----
#define PW1 0
#define PB1 16384
#define PW2 16512
#define PB2 32896
#define PGAMMA 33024
#define PBETA 33152
#define PMEAN 33280
#define PVAR 33408
#define PCLSW 33536
#define PCLSB 41728
#define PSIMW 41792
#define PSIMB 46912
#define PHOMW 46952
#define PHOMB 47080
#define PENTW 47081
#define PENTB 47209
#define PRAW_TOTAL 47210
#define PFW 47232
#define PFB 63616
#define PTOTAL 63744

__device__ __forceinline__ float uasf(unsigned u) { return __uint_as_float(u); }
__device__ __forceinline__ unsigned f2bu(float f) {
    bf16 h = __float2bfloat16(f);
    return (unsigned)*(unsigned short*)&h;
}

// ---------------- dtype detection ----------------
__global__ void detect_kernel(const void* __restrict__ x, const void* __restrict__ ei,
                              int* __restrict__ flags) {
    if (blockIdx.x != 0 || threadIdx.x != 0) return;
    const unsigned* xw = (const unsigned*)x;
    int votes = 0;
    for (int i = 0; i < 64; i++) {
        unsigned w = xw[i];
        unsigned e = (w >> 23) & 0xFFu;
        if (w == 0u || (e >= 90u && e <= 160u)) votes++;
    }
    flags[0] = (votes >= 48) ? 1 : 0;
    const unsigned* ew = (const unsigned*)ei;
    int zero_odd = 0;
    for (int i = 0; i < 64; i++)
        if (ew[2 * i + 1] == 0u) zero_odd++;
    flags[1] = (zero_odd >= 60) ? 1 : 0;
}

// ---------------- consolidated param convert ----------------
struct ParamSegs {
    const void* src[16];
    int dst[16];
};

__global__ void cvtparams_kernel(ParamSegs segs, float* __restrict__ params,
                                 const int* __restrict__ flags) {
    int idx = blockIdx.x * 256 + threadIdx.x;
    if (idx >= PRAW_TOTAL) return;
    int k = 0;
#pragma unroll
    for (int s = 1; s < 16; s++)
        if (idx >= segs.dst[s]) k = s;
    int rel = idx - segs.dst[k];
    const void* sp = segs.src[k];
    float v = flags[0] ? ((const float*)sp)[rel]
                       : __bfloat162float(((const bf16*)sp)[rel]);
    params[idx] = v;
}

// ---------------- edge load ----------------
__device__ __forceinline__ int load_edge(const int* __restrict__ ei, int which, int i, int i64) {
    size_t elem = (size_t)which * N_EDGES + (size_t)i;
    return i64 ? ei[elem * 2] : ei[elem];
}

// ---------------- fill: block-local LDS hist -> one reservation per (block,bucket) ----------
__global__ __launch_bounds__(256) void fill2_kernel(const int* __restrict__ ei,
                                                    int* __restrict__ bcur,
                                                    int* __restrict__ srcBuck,
                                                    const int* __restrict__ flags) {
    __shared__ int hist[NBUCK];
    __shared__ int gbase[NBUCK];
    __shared__ int lcur[NBUCK];
    int blk = blockIdx.x;
    int t = threadIdx.x;
    int i64 = flags[1];
    int e0 = blk * EPB;
    int ecnt = N_EDGES - e0;
    if (ecnt > EPB) ecnt = EPB;
    for (int i = t; i < NBUCK; i += 256) hist[i] = 0;
    __syncthreads();
    for (int i = t; i < ecnt; i += 256) {
        int c = load_edge(ei, 1, e0 + i, i64);
        atomicAdd(&hist[c >> 7], 1);
    }
    __syncthreads();
    for (int i = t; i < NBUCK; i += 256) {
        int c = hist[i];
        gbase[i] = (c > 0) ? atomicAdd(&bcur[i], c) : 0;
        lcur[i] = 0;
    }
    __syncthreads();
    for (int i = t; i < ecnt; i += 256) {
        int c = load_edge(ei, 1, e0 + i, i64);
        int r = load_edge(ei, 0, e0 + i, i64);
        int b = c >> 7;
        int p = gbase[b] + atomicAdd(&lcur[b], 1);
        if (p < BCAP) srcBuck[b * BCAP + p] = ((c & 127) << 17) | r;
    }
}

// ---------------- per-bucket degree count -> dinv ----------------
__global__ __launch_bounds__(256) void bucketcnt_kernel(const int* __restrict__ srcBuck,
                                                        const int* __restrict__ bcur,
                                                        float* __restrict__ dinv) {
    __shared__ int dcnt[128];
    int b = blockIdx.x;
    int t = threadIdx.x;
    if (t < 128) dcnt[t] = 0;
    __syncthreads();
    int cnt = bcur[b];
    if (cnt > BCAP) cnt = BCAP;
    for (int i = t; i < cnt; i += 256) atomicAdd(&dcnt[srcBuck[b * BCAP + i] >> 17], 1);
    __syncthreads();
    if (t < 128) {
        int n = (b << 7) + t;
        if (n < N_NODES) dinv[n] = rsqrtf((float)(dcnt[t] + 1));
    }
}

// ---------------- x -> bf16 prescaled by dinv ----------------
__global__ void cvtx_kernel(const void* __restrict__ x, const float* __restrict__ dinv,
                            unsigned short* __restrict__ B16, const int* __restrict__ flags) {
    int i4 = blockIdx.x * blockDim.x + threadIdx.x;
    if (i4 >= N_NODES * F / 4) return;
    int n = i4 >> 5;
    float d = dinv[n];
    float v0, v1, v2, v3;
    if (flags[0]) {
        float4 v = ((const float4*)x)[i4];
        v0 = v.x; v1 = v.y; v2 = v.z; v3 = v.w;
    } else {
        uint2 u = ((const uint2*)x)[i4];
        v0 = uasf(u.x << 16);
        v1 = uasf(u.x & 0xFFFF0000u);
        v2 = uasf(u.y << 16);
        v3 = uasf(u.y & 0xFFFF0000u);
    }
    uint2 o;
    o.x = f2bu(v0 * d) | (f2bu(v1 * d) << 16);
    o.y = f2bu(v2 * d) | (f2bu(v3 * d) << 16);
    ((uint2*)B16)[i4] = o;
}

// ---------------- fused W2 @ [cls|sim|hom|ent] precompute ----------------
__device__ __forceinline__ float headw(const float* __restrict__ p, int j, int c) {
    if (c < OUT_C) return p[PCLSW + j * OUT_C + c];
    if (c < OUT_C + NUM_CLASSES) return p[PSIMW + j * NUM_CLASSES + (c - OUT_C)];
    if (c == 104) return p[PHOMW + j];
    if (c == 105) return p[PENTW + j];
    return 0.f;
}

__global__ void fusew_kernel(float* __restrict__ params) {
    int idx = blockIdx.x * 256 + threadIdx.x;
    int k = idx >> 7;
    int c = idx & 127;
    float s = 0.f;
    for (int j = 0; j < 128; j++) s += params[PW2 + k * 128 + j] * headw(params, j, c);
    params[PFW + k * 128 + c] = s;
    if (k == 0) {
        float b = 0.f;
        for (int j = 0; j < 128; j++) b += params[PB2 + j] * headw(params, j, c);
        if (c < OUT_C) b += params[PCLSB + c];
        else if (c < OUT_C + NUM_CLASSES) b += params[PSIMB + c - OUT_C];
        else if (c == 104) b += params[PHOMB];
        else if (c == 105) b += params[PENTB];
        params[PFB + c] = b;
    }
}

// ---------------- W -> bf16 transposed ----------------
// wt1[n*128+k]  = W1[k][n]                      (k = true col of layer-1 input)
// wt2[n*128+p]  = Wfuse[colOf(p)][n]            (p = permuted position of h1 storage)
// colOf(p) = (p&7)*16 + (p>>3)   [inverse of p(c) = (c&15)*8 + (c>>4)]
__global__ void wcvt_kernel(const float* __restrict__ params, unsigned short* __restrict__ wt) {
    int idx = blockIdx.x * 256 + threadIdx.x;  // 32768
    if (idx >= 32768) return;
    int which = idx >> 14;
    int local = idx & 16383;
    int n = local >> 7;
    int k = local & 127;
    int ksrc = which ? ((k & 7) * 16 + (k >> 3)) : k;
    float v = params[(which ? PFW : PW1) + ksrc * 128 + n];
    wt[(which << 14) + n * 128 + k] = (unsigned short)f2bu(v);
}

// ---------------- Aggregation: LDS counting sort per bucket + uint4 gather ----------------
// Round-1 evidence: doubling occupancy left gather BW flat at ~3.2 TB/s -> the gather is
// throughput-capped by the L2-miss stream (random 256B granules over a 25.6MB array;
// per-XCD 4MB L2 hit ~16%). Fix = access-ORDER, not parallelism: counting-sort each
// bucket's edges by key (dest<<4 | src_chunk), chunk = src>>13 (8192 rows = 2MB of B16).
// Each 16-lane group still scans one dest's contiguous run (no extra instructions), but
// runs are chunk-ascending, and the whole grid is co-resident -> concurrent groups touch
// a narrow sliding source window that stays L2/L3-hot.
#define ACC8(u)                                \
    do {                                       \
        a[0] += uasf((u).x << 16);             \
        a[1] += uasf((u).x & 0xFFFF0000u);     \
        a[2] += uasf((u).y << 16);             \
        a[3] += uasf((u).y & 0xFFFF0000u);     \
        a[4] += uasf((u).z << 16);             \
        a[5] += uasf((u).z & 0xFFFF0000u);     \
        a[6] += uasf((u).w << 16);             \
        a[7] += uasf((u).w & 0xFFFF0000u);     \
    } while (0)

__global__ __launch_bounds__(512, 8) void agg_kernel(const unsigned short* __restrict__ B16,
                                                     unsigned short* __restrict__ G16,
                                                     const int* __restrict__ srcBuck,
                                                     const int* __restrict__ bcur,
                                                     const float* __restrict__ dinv) {
    __shared__ int raw[BCAP];
    __shared__ int sorted[BCAP];
    __shared__ int hist[2048];    // (dest<<4)|chunk : counts -> exclusive prefix -> scatter cursor
    __shared__ int part[512];
    __shared__ int dstart[129];   // per-dest run boundaries (chunk bins 13..15 are empty)
    int b = blockIdx.x;
    int t = threadIdx.x;
    int cnt = bcur[b];
    if (cnt > BCAP) cnt = BCAP;
    for (int i = t; i < 2048; i += 512) hist[i] = 0;
    __syncthreads();
    for (int i = t; i < cnt; i += 512) {
        int e = srcBuck[b * BCAP + i];
        raw[i] = e;
        int key = ((e >> 17) << 4) | ((e & 0x1FFFF) >> 13);
        atomicAdd(&hist[key], 1);
    }
    __syncthreads();
    // exclusive prefix over 2048 bins: 4 serial bins/thread + 512-wide block scan
    int b0 = hist[4 * t], b1 = hist[4 * t + 1], b2 = hist[4 * t + 2], b3 = hist[4 * t + 3];
    int s = b0 + b1 + b2 + b3;
    part[t] = s;
    __syncthreads();
    for (int d = 1; d < 512; d <<= 1) {
        int add = (t >= d) ? part[t - d] : 0;
        __syncthreads();
        part[t] += add;
        __syncthreads();
    }
    int ebase = part[t] - s;   // exclusive base for this thread's 4 bins
    hist[4 * t] = ebase;
    hist[4 * t + 1] = ebase + b0;
    hist[4 * t + 2] = ebase + b0 + b1;
    hist[4 * t + 3] = ebase + b0 + b1 + b2;
    __syncthreads();
    if (t < 128) dstart[t] = hist[t << 4];
    if (t == 0) dstart[128] = cnt;
    __syncthreads();
    for (int i = t; i < cnt; i += 512) {
        int e = raw[i];
        int key = ((e >> 17) << 4) | ((e & 0x1FFFF) >> 13);
        int p = atomicAdd(&hist[key], 1);
        sorted[p] = e & 0x1FFFF;
    }
    __syncthreads();

    int g16 = t >> 4;          // 0..31 gather groups of 16 lanes
    int hl8 = (t & 15) << 3;
    int base = b << 7;
    for (int d = g16; d < 128; d += 32) {
        int n = base + d;
        if (n >= N_NODES) break;
        float a[8] = {0.f, 0.f, 0.f, 0.f, 0.f, 0.f, 0.f, 0.f};
        {
            uint4 u = *(const uint4*)(B16 + ((size_t)n << 7) + hl8);
            ACC8(u);
        }
        int o = dstart[d], k = dstart[d + 1] - o;
        int j = 0;
        for (; j + 4 <= k; j += 4) {
            int s0 = sorted[o + j];
            int s1 = sorted[o + j + 1];
            int s2 = sorted[o + j + 2];
            int s3 = sorted[o + j + 3];
            uint4 u0 = *(const uint4*)(B16 + ((size_t)s0 << 7) + hl8);
            uint4 u1 = *(const uint4*)(B16 + ((size_t)s1 << 7) + hl8);
            uint4 u2 = *(const uint4*)(B16 + ((size_t)s2 << 7) + hl8);
            uint4 u3 = *(const uint4*)(B16 + ((size_t)s3 << 7) + hl8);
            ACC8(u0);
            ACC8(u1);
            ACC8(u2);
            ACC8(u3);
        }
        for (; j < k; j++) {
            int s0 = sorted[o + j];
            uint4 u0 = *(const uint4*)(B16 + ((size_t)s0 << 7) + hl8);
            ACC8(u0);
        }
        float dn = dinv[n];
        uint4 pk;
        pk.x = f2bu(a[0] * dn) | (f2bu(a[1] * dn) << 16);
        pk.y = f2bu(a[2] * dn) | (f2bu(a[3] * dn) << 16);
        pk.z = f2bu(a[4] * dn) | (f2bu(a[5] * dn) << 16);
        pk.w = f2bu(a[6] * dn) | (f2bu(a[7] * dn) << 16);
        *(uint4*)(G16 + ((size_t)n << 7) + hl8) = pk;
    }
}

// ---------------- MFMA GEMM, no LDS transpose: permuted-column output storage ------------
// Lane (m16, quad) after 32 MFMAs holds C[row = quad*4+reg][col = ct*16+m16], ct=0..7.
// mode1: h = bf16(ReLU(BN(C+b1))*dinv) stored at position p = m16*8+ct  -> uint4/row, coalesced.
// mode0: heads post fully in-register (row spread over 16 lanes x 8 regs; shfl_xor 1/2/4/8).
__global__ __launch_bounds__(256) void gemm_mfma_kernel(
    const unsigned short* __restrict__ A16, const unsigned short* __restrict__ Wt,
    unsigned short* __restrict__ outB, void* __restrict__ out,
    const float* __restrict__ params, const float* __restrict__ dinv, int mode,
    const int* __restrict__ flags) {
    __shared__ float sS[128], sO[128], sFB[128];
    int t = threadIdx.x;
    if (t < 128) {
        if (mode) {
            float s = rsqrtf(params[PVAR + t] + BN_EPS) * params[PGAMMA + t];
            sS[t] = s;
            sO[t] = params[PB1 + t] * s + (params[PBETA + t] - params[PMEAN + t] * s);
        } else {
            sFB[t] = params[PFB + t];
        }
    }
    __syncthreads();
    int wave = t >> 6, lane = t & 63, m16 = lane & 15, quad = lane >> 4;
    int rowbase = blockIdx.x * 64 + wave * 16;
    int rA = rowbase + m16;
    if (rA >= N_NODES) rA = N_NODES - 1;
    const size_t abase = (size_t)rA * 128 + (quad << 3);

    f32x4 acc[8];
#pragma unroll
    for (int ct = 0; ct < 8; ct++) acc[ct] = (f32x4){0.f, 0.f, 0.f, 0.f};

#pragma unroll
    for (int kk = 0; kk < 4; kk++) {
        bf16x8 af = *(const bf16x8*)(A16 + abase + kk * 32);
#pragma unroll
        for (int ct = 0; ct < 8; ct++) {
            bf16x8 bf = *(const bf16x8*)(Wt + (size_t)((ct * 16 + m16) * 128) + kk * 32 + (quad << 3));
            acc[ct] = __builtin_amdgcn_mfma_f32_16x16x32_bf16(af, bf, acc[ct], 0, 0, 0);
        }
    }

    int r0 = rowbase + quad * 4;
    if (mode) {
        float sc[8], of[8];
#pragma unroll
        for (int ct = 0; ct < 8; ct++) {
            sc[ct] = sS[ct * 16 + m16];
            of[ct] = sO[ct * 16 + m16];
        }
#pragma unroll
        for (int reg = 0; reg < 4; reg++) {
            int gr = r0 + reg;
            if (gr >= N_NODES) continue;
            float dn = dinv[gr];
            unsigned pk[4];
#pragma unroll
            for (int i = 0; i < 4; i++) {
                float v0 = fmaxf(acc[2 * i][reg] * sc[2 * i] + of[2 * i], 0.f) * dn;
                float v1 = fmaxf(acc[2 * i + 1][reg] * sc[2 * i + 1] + of[2 * i + 1], 0.f) * dn;
                pk[i] = f2bu(v0) | (f2bu(v1) << 16);
            }
            *(uint4*)(outB + (size_t)gr * 128 + (m16 << 3)) = make_uint4(pk[0], pk[1], pk[2], pk[3]);
        }
    } else {
        int isf = flags[0];
        const size_t OFF_SIM = (size_t)N_NODES * OUT_C;
        const size_t OFF_HOM = OFF_SIM + (size_t)N_NODES * NUM_CLASSES;
        const size_t OFF_ENT = OFF_HOM + (size_t)N_NODES;
        float* outf = (float*)out;
        bf16* outb = (bf16*)out;
        float fb[8];
#pragma unroll
        for (int ct = 0; ct < 8; ct++) fb[ct] = sFB[ct * 16 + m16];
#define STORE_OUT(idx, v)                        \
    do {                                         \
        if (isf) outf[(idx)] = (v);              \
        else outb[(idx)] = __float2bfloat16(v);  \
    } while (0)
#pragma unroll
        for (int reg = 0; reg < 4; reg++) {
            int gr = r0 + reg;
            bool vrow = (gr < N_NODES);
            float v[8];
#pragma unroll
            for (int ct = 0; ct < 8; ct++) v[ct] = acc[ct][reg] + fb[ct];
            // cls log_softmax over cols 0..63 (ct 0..3)
            float m = fmaxf(fmaxf(v[0], v[1]), fmaxf(v[2], v[3]));
            m = fmaxf(m, __shfl_xor(m, 1));
            m = fmaxf(m, __shfl_xor(m, 2));
            m = fmaxf(m, __shfl_xor(m, 4));
            m = fmaxf(m, __shfl_xor(m, 8));
            float S = expf(v[0] - m) + expf(v[1] - m) + expf(v[2] - m) + expf(v[3] - m);
            S += __shfl_xor(S, 1);
            S += __shfl_xor(S, 2);
            S += __shfl_xor(S, 4);
            S += __shfl_xor(S, 8);
            float lS = m + logf(S);
            if (vrow) {
#pragma unroll
                for (int ct = 0; ct < 4; ct++)
                    STORE_OUT((size_t)gr * OUT_C + ct * 16 + m16, v[ct] - lS);
            }
            // sim softmax over cols 64..103 (ct 4,5 all lanes; ct 6 iff m16<8)
            bool has6 = (m16 < 8);
            float s4 = v[4], s5 = v[5], s6 = has6 ? v[6] : -INFINITY;
            float m2 = fmaxf(fmaxf(s4, s5), s6);
            m2 = fmaxf(m2, __shfl_xor(m2, 1));
            m2 = fmaxf(m2, __shfl_xor(m2, 2));
            m2 = fmaxf(m2, __shfl_xor(m2, 4));
            m2 = fmaxf(m2, __shfl_xor(m2, 8));
            float e4 = expf(s4 - m2), e5 = expf(s5 - m2), e6 = has6 ? expf(s6 - m2) : 0.f;
            float S2 = e4 + e5 + e6;
            S2 += __shfl_xor(S2, 1);
            S2 += __shfl_xor(S2, 2);
            S2 += __shfl_xor(S2, 4);
            S2 += __shfl_xor(S2, 8);
            float rS2 = 1.f / S2;
            if (vrow) {
                STORE_OUT(OFF_SIM + (size_t)gr * NUM_CLASSES + m16, e4 * rS2);
                STORE_OUT(OFF_SIM + (size_t)gr * NUM_CLASSES + 16 + m16, e5 * rS2);
                if (has6) STORE_OUT(OFF_SIM + (size_t)gr * NUM_CLASSES + 32 + m16, e6 * rS2);
                if (m16 == 8) STORE_OUT(OFF_HOM + gr, 1.f / (1.f + expf(-v[6])));
                if (m16 == 9) STORE_OUT(OFF_ENT + gr, 1.f / (1.f + expf(-v[6])));
            }
        }
#undef STORE_OUT
    }
}

// ---------------- Launch ----------------
extern "C" void kernel_launch(void* const* d_in, const int* in_sizes, int n_in,
                              void* d_out, int out_size, void* d_ws, size_t ws_size,
                              hipStream_t stream) {
    const void* x = d_in[0];
    const int* ei = (const int*)d_in[1];

    char* ws = (char*)d_ws;
    size_t o = 0;
    auto alloc = [&](size_t bytes) {
        size_t r = o;
        o = (o + bytes + 255) & ~(size_t)255;
        return r;
    };
    char* RA = ws + alloc((size_t)51 * 1024 * 1024);   // srcBuck + B16
    char* RB = ws + alloc((size_t)26 * 1024 * 1024);   // G16
    float* params = (float*)(ws + alloc((size_t)PTOTAL * 4));
    unsigned short* wt = (unsigned short*)(ws + alloc(65536));
    float* dinv = (float*)(ws + alloc((size_t)N_NODES * 4));
    int* bcur = (int*)(ws + alloc((size_t)(NBUCK + 8) * 4));
    int* flags = (int*)(ws + alloc(256));

    int* srcBuck = (int*)RA;                                          // 12.81 MB
    unsigned short* B16 = (unsigned short*)(RA + 13u * 1024 * 1024);  // 25.6 MB
    unsigned short* G16 = (unsigned short*)RB;                        // 25.6 MB

    detect_kernel<<<1, 64, 0, stream>>>(x, ei, flags);
    hipMemsetAsync(bcur, 0, (size_t)(NBUCK + 8) * 4, stream);

    ParamSegs segs;
    const int srcIdx[16] = {2, 3, 4, 5, 6, 7, 8, 9, 10, 11, 12, 13, 14, 15, 16, 17};
    const int dsts[16] = {PW1, PB1, PW2, PB2, PGAMMA, PBETA, PMEAN, PVAR,
                          PCLSW, PCLSB, PSIMW, PSIMB, PHOMW, PHOMB, PENTW, PENTB};
    for (int k = 0; k < 16; k++) {
        segs.src[k] = d_in[srcIdx[k]];
        segs.dst[k] = dsts[k];
    }
    cvtparams_kernel<<<(PRAW_TOTAL + 255) / 256, 256, 0, stream>>>(segs, params, flags);
    fusew_kernel<<<64, 256, 0, stream>>>(params);
    wcvt_kernel<<<128, 256, 0, stream>>>(params, wt);

    fill2_kernel<<<FILL_BLOCKS, 256, 0, stream>>>(ei, bcur, srcBuck, flags);
    bucketcnt_kernel<<<NBUCK, 256, 0, stream>>>(srcBuck, bcur, dinv);
    cvtx_kernel<<<(N_NODES * F / 4 + 255) / 256, 256, 0, stream>>>(x, dinv, B16, flags);

    const int gemmGrid = (N_NODES + 63) / 64;

    // layer 1: g1 = A_hat x ; h1 = bf16(ReLU(BN(g1 @ W1 + b1)) * dinv)  [permuted cols]
    agg_kernel<<<NBUCK, 512, 0, stream>>>(B16, G16, srcBuck, bcur, dinv);
    gemm_mfma_kernel<<<gemmGrid, 256, 0, stream>>>(G16, wt, B16, nullptr, params, dinv, 1, flags);
    // layer 2 + fused heads + post: g2 = A_hat h1 ; out = post(g2 @ Wfuse' + bfuse)
    agg_kernel<<<NBUCK, 512, 0, stream>>>(B16, G16, srcBuck, bcur, dinv);
    gemm_mfma_kernel<<<gemmGrid, 256, 0, stream>>>(G16, wt + 16384, nullptr, d_out, params, dinv, 0, flags);
}

// Round 3
// 431.724 us; speedup vs baseline: 1.0729x; 1.0729x over previous
//
#include <hip/hip_runtime.h>
#include <hip/hip_bf16.h>
#include <math.h>

#define N_NODES 100000
#define N_EDGES 1600000
#define F 128
#define OUT_C 64
#define NUM_CLASSES 40
#define BN_EPS 1e-5f

#define NBUCK 782   // ceil(100000/128) buckets of 128 destination nodes
#define BCAP 4096   // per-bucket edge capacity
#define FILL_BLOCKS 512
#define EPB ((N_EDGES + FILL_BLOCKS - 1) / FILL_BLOCKS)  // 3125

#define TSTRIDE 136  // LDS tile stride in bf16: 272B = 16B-aligned, bank-stride 4 -> 2-way (free)

typedef __hip_bfloat16 bf16;
typedef __attribute__((ext_vector_type(8))) short bf16x8;
typedef __attribute__((ext_vector_type(4))) float f32x4;

// ---- fp32 param block offsets ----
#define PW1 0
#define PB1 16384
#define PW2 16512
#define PB2 32896
#define PGAMMA 33024
#define PBETA 33152
#define PMEAN 33280
#define PVAR 33408
#define PCLSW 33536
#define PCLSB 41728
#define PSIMW 41792
#define PSIMB 46912
#define PHOMW 46952
#define PHOMB 47080
#define PENTW 47081
#define PENTB 47209
#define PRAW_TOTAL 47210
#define PFW 47232
#define PFB 63616
#define PTOTAL 63744

__device__ __forceinline__ float uasf(unsigned u) { return __uint_as_float(u); }
__device__ __forceinline__ unsigned f2bu(float f) {
    bf16 h = __float2bfloat16(f);
    return (unsigned)*(unsigned short*)&h;
}

// ---------------- dtype detection ----------------
__global__ void detect_kernel(const void* __restrict__ x, const void* __restrict__ ei,
                              int* __restrict__ flags) {
    if (blockIdx.x != 0 || threadIdx.x != 0) return;
    const unsigned* xw = (const unsigned*)x;
    int votes = 0;
    for (int i = 0; i < 64; i++) {
        unsigned w = xw[i];
        unsigned e = (w >> 23) & 0xFFu;
        if (w == 0u || (e >= 90u && e <= 160u)) votes++;
    }
    flags[0] = (votes >= 48) ? 1 : 0;
    const unsigned* ew = (const unsigned*)ei;
    int zero_odd = 0;
    for (int i = 0; i < 64; i++)
        if (ew[2 * i + 1] == 0u) zero_odd++;
    flags[1] = (zero_odd >= 60) ? 1 : 0;
}

// ---------------- consolidated param convert ----------------
struct ParamSegs {
    const void* src[16];
    int dst[16];
};

__global__ void cvtparams_kernel(ParamSegs segs, float* __restrict__ params,
                                 const int* __restrict__ flags) {
    int idx = blockIdx.x * 256 + threadIdx.x;
    if (idx >= PRAW_TOTAL) return;
    int k = 0;
#pragma unroll
    for (int s = 1; s < 16; s++)
        if (idx >= segs.dst[s]) k = s;
    int rel = idx - segs.dst[k];
    const void* sp = segs.src[k];
    float v = flags[0] ? ((const float*)sp)[rel]
                       : __bfloat162float(((const bf16*)sp)[rel]);
    params[idx] = v;
}

// ---------------- edge load ----------------
__device__ __forceinline__ int load_edge(const int* __restrict__ ei, int which, int i, int i64) {
    size_t elem = (size_t)which * N_EDGES + (size_t)i;
    return i64 ? ei[elem * 2] : ei[elem];
}

// ---------------- fill: block-local LDS hist -> one reservation per (block,bucket) ----------
__global__ __launch_bounds__(256) void fill2_kernel(const int* __restrict__ ei,
                                                    int* __restrict__ bcur,
                                                    int* __restrict__ srcBuck,
                                                    const int* __restrict__ flags) {
    __shared__ int hist[NBUCK];
    __shared__ int gbase[NBUCK];
    __shared__ int lcur[NBUCK];
    int blk = blockIdx.x;
    int t = threadIdx.x;
    int i64 = flags[1];
    int e0 = blk * EPB;
    int ecnt = N_EDGES - e0;
    if (ecnt > EPB) ecnt = EPB;
    for (int i = t; i < NBUCK; i += 256) hist[i] = 0;
    __syncthreads();
    for (int i = t; i < ecnt; i += 256) {
        int c = load_edge(ei, 1, e0 + i, i64);
        atomicAdd(&hist[c >> 7], 1);
    }
    __syncthreads();
    for (int i = t; i < NBUCK; i += 256) {
        int c = hist[i];
        gbase[i] = (c > 0) ? atomicAdd(&bcur[i], c) : 0;
        lcur[i] = 0;
    }
    __syncthreads();
    for (int i = t; i < ecnt; i += 256) {
        int c = load_edge(ei, 1, e0 + i, i64);
        int r = load_edge(ei, 0, e0 + i, i64);
        int b = c >> 7;
        int p = gbase[b] + atomicAdd(&lcur[b], 1);
        if (p < BCAP) srcBuck[b * BCAP + p] = ((c & 127) << 17) | r;
    }
}

// ---------------- per-bucket degree count -> dinv ----------------
__global__ __launch_bounds__(256) void bucketcnt_kernel(const int* __restrict__ srcBuck,
                                                        const int* __restrict__ bcur,
                                                        float* __restrict__ dinv) {
    __shared__ int dcnt[128];
    int b = blockIdx.x;
    int t = threadIdx.x;
    if (t < 128) dcnt[t] = 0;
    __syncthreads();
    int cnt = bcur[b];
    if (cnt > BCAP) cnt = BCAP;
    for (int i = t; i < cnt; i += 256) atomicAdd(&dcnt[srcBuck[b * BCAP + i] >> 17], 1);
    __syncthreads();
    if (t < 128) {
        int n = (b << 7) + t;
        if (n < N_NODES) dinv[n] = rsqrtf((float)(dcnt[t] + 1));
    }
}

// ---------------- x -> bf16 prescaled by dinv ----------------
__global__ void cvtx_kernel(const void* __restrict__ x, const float* __restrict__ dinv,
                            unsigned short* __restrict__ B16, const int* __restrict__ flags) {
    int i4 = blockIdx.x * blockDim.x + threadIdx.x;
    if (i4 >= N_NODES * F / 4) return;
    int n = i4 >> 5;
    float d = dinv[n];
    float v0, v1, v2, v3;
    if (flags[0]) {
        float4 v = ((const float4*)x)[i4];
        v0 = v.x; v1 = v.y; v2 = v.z; v3 = v.w;
    } else {
        uint2 u = ((const uint2*)x)[i4];
        v0 = uasf(u.x << 16);
        v1 = uasf(u.x & 0xFFFF0000u);
        v2 = uasf(u.y << 16);
        v3 = uasf(u.y & 0xFFFF0000u);
    }
    uint2 o;
    o.x = f2bu(v0 * d) | (f2bu(v1 * d) << 16);
    o.y = f2bu(v2 * d) | (f2bu(v3 * d) << 16);
    ((uint2*)B16)[i4] = o;
}

// ---------------- fused W2 @ [cls|sim|hom|ent] precompute ----------------
__device__ __forceinline__ float headw(const float* __restrict__ p, int j, int c) {
    if (c < OUT_C) return p[PCLSW + j * OUT_C + c];
    if (c < OUT_C + NUM_CLASSES) return p[PSIMW + j * NUM_CLASSES + (c - OUT_C)];
    if (c == 104) return p[PHOMW + j];
    if (c == 105) return p[PENTW + j];
    return 0.f;
}

__global__ void fusew_kernel(float* __restrict__ params) {
    int idx = blockIdx.x * 256 + threadIdx.x;
    int k = idx >> 7;
    int c = idx & 127;
    float s = 0.f;
    for (int j = 0; j < 128; j++) s += params[PW2 + k * 128 + j] * headw(params, j, c);
    params[PFW + k * 128 + c] = s;
    if (k == 0) {
        float b = 0.f;
        for (int j = 0; j < 128; j++) b += params[PB2 + j] * headw(params, j, c);
        if (c < OUT_C) b += params[PCLSB + c];
        else if (c < OUT_C + NUM_CLASSES) b += params[PSIMB + c - OUT_C];
        else if (c == 104) b += params[PHOMB];
        else if (c == 105) b += params[PENTB];
        params[PFB + c] = b;
    }
}

// ---------------- W -> bf16 transposed ----------------
// wt1[n*128+k]  = W1[k][n]                      (k = true col of layer-1 input)
// wt2[n*128+p]  = Wfuse[colOf(p)][n]            (p = permuted position of h1 storage)
// colOf(p) = (p&7)*16 + (p>>3)   [inverse of p(c) = (c&15)*8 + (c>>4)]
__global__ void wcvt_kernel(const float* __restrict__ params, unsigned short* __restrict__ wt) {
    int idx = blockIdx.x * 256 + threadIdx.x;  // 32768
    if (idx >= 32768) return;
    int which = idx >> 14;
    int local = idx & 16383;
    int n = local >> 7;
    int k = local & 127;
    int ksrc = which ? ((k & 7) * 16 + (k >> 3)) : k;
    float v = params[(which ? PFW : PW1) + ksrc * 128 + n];
    wt[(which << 14) + n * 128 + k] = (unsigned short)f2bu(v);
}

// ---------------- Fused aggregation + MFMA GEMM + epilogue, one bucket per block -------
// R2 evidence: FETCH=184MB is the compulsory per-XCD L2-fill floor (8 XCDs x 25.6MB) and
// its serve rate is pinned at ~3.2 TB/s regardless of occupancy/order -> gather is at its
// floor. Remaining lever: delete the intermediate g tensor. The block already owns the
// full 128x128 output tile; stage it in LDS (stride 136 bf16: 16B-aligned, 2-way-free
// banks) and run the 256 MFMAs + epilogue in-block. Saves 51.2MB traffic + 1 launch per
// layer. Flow: B16 -> (L1) -> G16 -> (L2) -> out, so no gather/overwrite aliasing.
#define ACC8(u)                                \
    do {                                       \
        a[0] += uasf((u).x << 16);             \
        a[1] += uasf((u).x & 0xFFFF0000u);     \
        a[2] += uasf((u).y << 16);             \
        a[3] += uasf((u).y & 0xFFFF0000u);     \
        a[4] += uasf((u).z << 16);             \
        a[5] += uasf((u).z & 0xFFFF0000u);     \
        a[6] += uasf((u).w << 16);             \
        a[7] += uasf((u).w & 0xFFFF0000u);     \
    } while (0)

__global__ __launch_bounds__(512, 4) void aggemm_kernel(
    const unsigned short* __restrict__ IN16, const unsigned short* __restrict__ Wt,
    unsigned short* __restrict__ outB, void* __restrict__ out,
    const float* __restrict__ params, const float* __restrict__ dinv,
    const int* __restrict__ srcBuck, const int* __restrict__ bcur,
    int mode, const int* __restrict__ flags) {
    __shared__ int sorted[BCAP];                       // 16 KB, persists through gather
    __shared__ int dcnt[128], doff[128], dcur[128];
    __shared__ float sC1[128], sC2[128];
    __shared__ __align__(16) char scratch[128 * TSTRIDE * 2];  // raw(16KB) -> tile(34KB)
    int* raw = (int*)scratch;
    unsigned short* tile = (unsigned short*)scratch;

    int b = blockIdx.x;
    int t = threadIdx.x;

    if (t < 128) {
        if (mode) {
            float s = rsqrtf(params[PVAR + t] + BN_EPS) * params[PGAMMA + t];
            sC1[t] = s;
            sC2[t] = params[PB1 + t] * s + (params[PBETA + t] - params[PMEAN + t] * s);
        } else {
            sC1[t] = params[PFB + t];
        }
        dcnt[t] = 0;
    }
    __syncthreads();

    int cnt = bcur[b];
    if (cnt > BCAP) cnt = BCAP;
    for (int i = t; i < cnt; i += 512) {
        int e = srcBuck[b * BCAP + i];
        raw[i] = e;
        atomicAdd(&dcnt[e >> 17], 1);
    }
    __syncthreads();
    if (t < 128) doff[t] = dcnt[t];
    __syncthreads();
    for (int d = 1; d < 128; d <<= 1) {
        int add = 0;
        if (t < 128 && t >= d) add = doff[t - d];
        __syncthreads();
        if (t < 128) doff[t] += add;
        __syncthreads();
    }
    if (t < 128) {
        doff[t] -= dcnt[t];
        dcur[t] = 0;
    }
    __syncthreads();
    for (int i = t; i < cnt; i += 512) {
        int e = raw[i];
        int d = e >> 17;
        int r = atomicAdd(&dcur[d], 1);
        sorted[doff[d] + r] = e & 0x1FFFF;
    }
    __syncthreads();
    // raw[] is dead from here; tile overlays scratch.

    int g16 = t >> 4;          // 0..31 gather groups of 16 lanes
    int hl8 = (t & 15) << 3;
    int base = b << 7;
    for (int d = g16; d < 128; d += 32) {
        int n = base + d;
        uint4 pk = make_uint4(0u, 0u, 0u, 0u);
        if (n < N_NODES) {
            float a[8] = {0.f, 0.f, 0.f, 0.f, 0.f, 0.f, 0.f, 0.f};
            {
                uint4 u = *(const uint4*)(IN16 + ((size_t)n << 7) + hl8);
                ACC8(u);
            }
            int o = doff[d], k = dcnt[d];
            int j = 0;
            for (; j + 4 <= k; j += 4) {
                int s0 = sorted[o + j];
                int s1 = sorted[o + j + 1];
                int s2 = sorted[o + j + 2];
                int s3 = sorted[o + j + 3];
                uint4 u0 = *(const uint4*)(IN16 + ((size_t)s0 << 7) + hl8);
                uint4 u1 = *(const uint4*)(IN16 + ((size_t)s1 << 7) + hl8);
                uint4 u2 = *(const uint4*)(IN16 + ((size_t)s2 << 7) + hl8);
                uint4 u3 = *(const uint4*)(IN16 + ((size_t)s3 << 7) + hl8);
                ACC8(u0);
                ACC8(u1);
                ACC8(u2);
                ACC8(u3);
            }
            for (; j < k; j++) {
                int s0 = sorted[o + j];
                uint4 u0 = *(const uint4*)(IN16 + ((size_t)s0 << 7) + hl8);
                ACC8(u0);
            }
            float dn = dinv[n];
            pk.x = f2bu(a[0] * dn) | (f2bu(a[1] * dn) << 16);
            pk.y = f2bu(a[2] * dn) | (f2bu(a[3] * dn) << 16);
            pk.z = f2bu(a[4] * dn) | (f2bu(a[5] * dn) << 16);
            pk.w = f2bu(a[6] * dn) | (f2bu(a[7] * dn) << 16);
        }
        *(uint4*)((char*)tile + (size_t)d * (TSTRIDE * 2) + (hl8 << 1)) = pk;
    }
    __syncthreads();

    // ---- MFMA phase: 8 waves x 16 rows, A from LDS tile, B (Wt) from global (L2-hot) ----
    int w = t >> 6, lane = t & 63, m16 = lane & 15, quad = lane >> 4;
    int rloc = w * 16 + m16;

    f32x4 acc[8];
#pragma unroll
    for (int ct = 0; ct < 8; ct++) acc[ct] = (f32x4){0.f, 0.f, 0.f, 0.f};

#pragma unroll
    for (int kk = 0; kk < 4; kk++) {
        bf16x8 af = *(const bf16x8*)((char*)tile + (size_t)rloc * (TSTRIDE * 2) + kk * 64 + quad * 16);
#pragma unroll
        for (int ct = 0; ct < 8; ct++) {
            bf16x8 bfr = *(const bf16x8*)(Wt + (size_t)((ct * 16 + m16) * 128) + kk * 32 + (quad << 3));
            acc[ct] = __builtin_amdgcn_mfma_f32_16x16x32_bf16(af, bfr, acc[ct], 0, 0, 0);
        }
    }

    int rowbase = base + w * 16;
    int r0 = rowbase + quad * 4;
    if (mode) {
        float sc[8], of[8];
#pragma unroll
        for (int ct = 0; ct < 8; ct++) {
            sc[ct] = sC1[ct * 16 + m16];
            of[ct] = sC2[ct * 16 + m16];
        }
#pragma unroll
        for (int reg = 0; reg < 4; reg++) {
            int gr = r0 + reg;
            if (gr >= N_NODES) continue;
            float dn = dinv[gr];
            unsigned pk[4];
#pragma unroll
            for (int i = 0; i < 4; i++) {
                float v0 = fmaxf(acc[2 * i][reg] * sc[2 * i] + of[2 * i], 0.f) * dn;
                float v1 = fmaxf(acc[2 * i + 1][reg] * sc[2 * i + 1] + of[2 * i + 1], 0.f) * dn;
                pk[i] = f2bu(v0) | (f2bu(v1) << 16);
            }
            *(uint4*)(outB + (size_t)gr * 128 + (m16 << 3)) = make_uint4(pk[0], pk[1], pk[2], pk[3]);
        }
    } else {
        int isf = flags[0];
        const size_t OFF_SIM = (size_t)N_NODES * OUT_C;
        const size_t OFF_HOM = OFF_SIM + (size_t)N_NODES * NUM_CLASSES;
        const size_t OFF_ENT = OFF_HOM + (size_t)N_NODES;
        float* outf = (float*)out;
        bf16* outb = (bf16*)out;
        float fb[8];
#pragma unroll
        for (int ct = 0; ct < 8; ct++) fb[ct] = sC1[ct * 16 + m16];
#define STORE_OUT(idx, v)                        \
    do {                                         \
        if (isf) outf[(idx)] = (v);              \
        else outb[(idx)] = __float2bfloat16(v);  \
    } while (0)
#pragma unroll
        for (int reg = 0; reg < 4; reg++) {
            int gr = r0 + reg;
            bool vrow = (gr < N_NODES);
            float v[8];
#pragma unroll
            for (int ct = 0; ct < 8; ct++) v[ct] = acc[ct][reg] + fb[ct];
            // cls log_softmax over cols 0..63 (ct 0..3)
            float m = fmaxf(fmaxf(v[0], v[1]), fmaxf(v[2], v[3]));
            m = fmaxf(m, __shfl_xor(m, 1));
            m = fmaxf(m, __shfl_xor(m, 2));
            m = fmaxf(m, __shfl_xor(m, 4));
            m = fmaxf(m, __shfl_xor(m, 8));
            float S = expf(v[0] - m) + expf(v[1] - m) + expf(v[2] - m) + expf(v[3] - m);
            S += __shfl_xor(S, 1);
            S += __shfl_xor(S, 2);
            S += __shfl_xor(S, 4);
            S += __shfl_xor(S, 8);
            float lS = m + logf(S);
            if (vrow) {
#pragma unroll
                for (int ct = 0; ct < 4; ct++)
                    STORE_OUT((size_t)gr * OUT_C + ct * 16 + m16, v[ct] - lS);
            }
            // sim softmax over cols 64..103 (ct 4,5 all lanes; ct 6 iff m16<8)
            bool has6 = (m16 < 8);
            float s4 = v[4], s5 = v[5], s6 = has6 ? v[6] : -INFINITY;
            float m2 = fmaxf(fmaxf(s4, s5), s6);
            m2 = fmaxf(m2, __shfl_xor(m2, 1));
            m2 = fmaxf(m2, __shfl_xor(m2, 2));
            m2 = fmaxf(m2, __shfl_xor(m2, 4));
            m2 = fmaxf(m2, __shfl_xor(m2, 8));
            float e4 = expf(s4 - m2), e5 = expf(s5 - m2), e6 = has6 ? expf(s6 - m2) : 0.f;
            float S2 = e4 + e5 + e6;
            S2 += __shfl_xor(S2, 1);
            S2 += __shfl_xor(S2, 2);
            S2 += __shfl_xor(S2, 4);
            S2 += __shfl_xor(S2, 8);
            float rS2 = 1.f / S2;
            if (vrow) {
                STORE_OUT(OFF_SIM + (size_t)gr * NUM_CLASSES + m16, e4 * rS2);
                STORE_OUT(OFF_SIM + (size_t)gr * NUM_CLASSES + 16 + m16, e5 * rS2);
                if (has6) STORE_OUT(OFF_SIM + (size_t)gr * NUM_CLASSES + 32 + m16, e6 * rS2);
                if (m16 == 8) STORE_OUT(OFF_HOM + gr, 1.f / (1.f + expf(-v[6])));
                if (m16 == 9) STORE_OUT(OFF_ENT + gr, 1.f / (1.f + expf(-v[6])));
            }
        }
#undef STORE_OUT
    }
}

// ---------------- Launch ----------------
extern "C" void kernel_launch(void* const* d_in, const int* in_sizes, int n_in,
                              void* d_out, int out_size, void* d_ws, size_t ws_size,
                              hipStream_t stream) {
    const void* x = d_in[0];
    const int* ei = (const int*)d_in[1];

    char* ws = (char*)d_ws;
    size_t o = 0;
    auto alloc = [&](size_t bytes) {
        size_t r = o;
        o = (o + bytes + 255) & ~(size_t)255;
        return r;
    };
    char* RA = ws + alloc((size_t)51 * 1024 * 1024);   // srcBuck + B16
    char* RB = ws + alloc((size_t)26 * 1024 * 1024);   // G16
    float* params = (float*)(ws + alloc((size_t)PTOTAL * 4));
    unsigned short* wt = (unsigned short*)(ws + alloc(65536));
    float* dinv = (float*)(ws + alloc((size_t)N_NODES * 4));
    int* bcur = (int*)(ws + alloc((size_t)(NBUCK + 8) * 4));
    int* flags = (int*)(ws + alloc(256));

    int* srcBuck = (int*)RA;                                          // 12.81 MB
    unsigned short* B16 = (unsigned short*)(RA + 13u * 1024 * 1024);  // 25.6 MB
    unsigned short* G16 = (unsigned short*)RB;                        // 25.6 MB (h1)

    detect_kernel<<<1, 64, 0, stream>>>(x, ei, flags);
    hipMemsetAsync(bcur, 0, (size_t)(NBUCK + 8) * 4, stream);

    ParamSegs segs;
    const int srcIdx[16] = {2, 3, 4, 5, 6, 7, 8, 9, 10, 11, 12, 13, 14, 15, 16, 17};
    const int dsts[16] = {PW1, PB1, PW2, PB2, PGAMMA, PBETA, PMEAN, PVAR,
                          PCLSW, PCLSB, PSIMW, PSIMB, PHOMW, PHOMB, PENTW, PENTB};
    for (int k = 0; k < 16; k++) {
        segs.src[k] = d_in[srcIdx[k]];
        segs.dst[k] = dsts[k];
    }
    cvtparams_kernel<<<(PRAW_TOTAL + 255) / 256, 256, 0, stream>>>(segs, params, flags);
    fusew_kernel<<<64, 256, 0, stream>>>(params);
    wcvt_kernel<<<128, 256, 0, stream>>>(params, wt);

    fill2_kernel<<<FILL_BLOCKS, 256, 0, stream>>>(ei, bcur, srcBuck, flags);
    bucketcnt_kernel<<<NBUCK, 256, 0, stream>>>(srcBuck, bcur, dinv);
    cvtx_kernel<<<(N_NODES * F / 4 + 255) / 256, 256, 0, stream>>>(x, dinv, B16, flags);

    // layer 1 fused: h1 = bf16(ReLU(BN((A_hat x) @ W1 + b1)) * dinv)  [permuted cols] -> G16
    aggemm_kernel<<<NBUCK, 512, 0, stream>>>(B16, wt, G16, nullptr, params, dinv,
                                             srcBuck, bcur, 1, flags);
    // layer 2 fused: out = post((A_hat h1) @ Wfuse' + bfuse)
    aggemm_kernel<<<NBUCK, 512, 0, stream>>>(G16, wt + 16384, nullptr, d_out, params, dinv,
                                             srcBuck, bcur, 0, flags);
}